// Round 8
// baseline (534.717 us; speedup 1.0000x reference)
//
#include <hip/hip_runtime.h>
#include <math.h>

#define IMG_H 512
#define IMG_W 512
#define N_IMG 96            // 32 * 3
#define TW 32               // tile width (output cols)
#define TH 32               // tile height (output rows)
#define KS 11
#define IN_ROWS 42          // TH + 10
#define NUNITS (IN_ROWS * 8)    // 336 horizontal-conv units (4 px each)
#define STRIDE 33           // odd LDS row stride -> 2-way banks (free)
#define PLANE (IN_ROWS * STRIDE)   // 1386
#define NBLOCKS (N_IMG * (IMG_W / TW) * (IMG_H / TH))   // 96*256 = 24576
#define TOTAL_N 25165824.0  // 32*3*512*512

// Round-7 design:
//  - u/v basis: u=x+y, v=x-y. Only FOUR conv maps needed:
//      conv(u), conv(v), conv(u^2), conv(v^2)
//    since 2*mux*muy = (muu^2-muv^2)/2, mux^2+muy^2 = (muu^2+muv^2)/2,
//    conv(xy) = (Suu-Svv)/4, conv(x^2)+conv(y^2) = (Suu+Svv)/2.
//    -> 20% fewer conv FMAs + 20% less LDS traffic than 5-map form.
//  - 32x32 tiles: h-pass overhead (TH+10)/TH = 1.31 (was 1.625).
//  - Round-5 gather-then-convolve structure (round 6 proved streaming
//    schedules worse), nothing live across barriers.
//  - LDS: 4 planes * 1386 * 4B = 22.2 KB -> 6 blocks/CU, 24 waves/CU.
//  - Banks: writes (33r+4cg+e)%32=(r+4cg+e)%32 -> 2-way; reads
//    (33row+col)%32=(row+col)%32, col=tid&31, row=+4*(tid>>5) -> 2-way. Free.

__global__ __launch_bounds__(256, 6) void ssim_tile_kernel(
    const float* __restrict__ pred, const float* __restrict__ targ,
    const float* __restrict__ k2d, float* __restrict__ partial)
{
    __shared__ float H[4][PLANE];
    __shared__ float wsum[4];

    const int tid = threadIdx.x;
    const int bid = blockIdx.x;
    const int img = bid >> 8;          // 256 tiles per image
    const int tin = bid & 255;
    const int ty  = tin >> 4;          // 16 tiles per dim
    const int tx  = tin & 15;
    const int y0  = ty * TH;
    const int x0  = tx * TW;

    // exact 1D gaussian from the 2D kernel: k2d[5][j] = g5 * g[j], k2d[5][5] = g5^2
    float g[KS];
    {
        const float inv = rsqrtf(k2d[5 * KS + 5]);
        #pragma unroll
        for (int j = 0; j < KS; ++j) g[j] = k2d[5 * KS + j] * inv;
    }

    const float* __restrict__ Pimg = pred + (size_t)img * (IMG_H * IMG_W);
    const float* __restrict__ Timg = targ + (size_t)img * (IMG_H * IMG_W);

    // ---- stage 1: horizontal 11-tap pass on u,v,u^2,v^2 -> LDS planes ----
    #pragma unroll
    for (int b = 0; b < 2; ++b) {
        const int u = tid + (b << 8);
        if (u < NUNITS) {
            const int r    = u >> 3;           // 0..41
            const int cg   = u & 7;            // 0..7
            const int gr   = y0 - 5 + r;
            const int col0 = x0 + (cg << 2) - 8;   // 16B-aligned window start
            const bool rowok = ((unsigned)gr < (unsigned)IMG_H);
            const float* rowP = Pimg + (size_t)(rowok ? gr : 0) * IMG_W;
            const float* rowT = Timg + (size_t)(rowok ? gr : 0) * IMG_W;

            float p[20], t[20];
            if (rowok && col0 >= 0 && col0 + 20 <= IMG_W) {
                #pragma unroll
                for (int q = 0; q < 5; ++q) {
                    const float4 vp = *(const float4*)(rowP + col0 + 4 * q);
                    const float4 vt = *(const float4*)(rowT + col0 + 4 * q);
                    p[4*q+0] = vp.x; p[4*q+1] = vp.y; p[4*q+2] = vp.z; p[4*q+3] = vp.w;
                    t[4*q+0] = vt.x; t[4*q+1] = vt.y; t[4*q+2] = vt.z; t[4*q+3] = vt.w;
                }
            } else {
                #pragma unroll
                for (int e = 0; e < 20; ++e) {
                    const int c  = col0 + e;
                    const int cc = min(max(c, 0), IMG_W - 1);
                    const bool ok = rowok && (c >= 0) && (c < IMG_W);
                    const float pv = rowP[cc];
                    const float tv = rowT[cc];
                    p[e] = ok ? pv : 0.0f;
                    t[e] = ok ? tv : 0.0f;
                }
            }

            // transform to u,v in place over the used range (elems 3..17)
            #pragma unroll
            for (int i = 0; i < 15; ++i) {
                const float pv = p[3 + i];
                const float tv = t[3 + i];
                p[3 + i] = pv + tv;     // u
                t[3 + i] = pv - tv;     // v
            }

            // mu convs of u,v
            float au[4], av[4];
            #pragma unroll
            for (int k = 0; k < 4; ++k) { au[k] = 0.f; av[k] = 0.f; }
            #pragma unroll
            for (int k = 0; k < 4; ++k) {
                #pragma unroll
                for (int j = 0; j < KS; ++j) {
                    au[k] = fmaf(g[j], p[3 + k + j], au[k]);
                    av[k] = fmaf(g[j], t[3 + k + j], av[k]);
                }
            }
            // square in place, then second-moment convs
            #pragma unroll
            for (int i = 0; i < 15; ++i) {
                p[3 + i] *= p[3 + i];   // u^2
                t[3 + i] *= t[3 + i];   // v^2
            }
            float auu[4], avv[4];
            #pragma unroll
            for (int k = 0; k < 4; ++k) { auu[k] = 0.f; avv[k] = 0.f; }
            #pragma unroll
            for (int k = 0; k < 4; ++k) {
                #pragma unroll
                for (int j = 0; j < KS; ++j) {
                    auu[k] = fmaf(g[j], p[3 + k + j], auu[k]);
                    avv[k] = fmaf(g[j], t[3 + k + j], avv[k]);
                }
            }

            const int wb = r * STRIDE + (cg << 2);
            #pragma unroll
            for (int e = 0; e < 4; ++e) {
                H[0][wb + e] = au[e];
                H[1][wb + e] = av[e];
                H[2][wb + e] = auu[e];
                H[3][wb + e] = avv[e];
            }
        }
    }
    __syncthreads();

    // ---- stage 2: vertical 11-tap pass + SSIM formula ----
    const int col  = tid & 31;
    const int rg   = tid >> 5;          // 0..7, rows rg*4 .. rg*4+3
    const int base = rg * 4 * STRIDE + col;

    float vu[14], vv[14], vuu[14], vvv[14];
    #pragma unroll
    for (int i = 0; i < 14; ++i) {
        const int idx = base + i * STRIDE;
        vu [i] = H[0][idx];
        vv [i] = H[1][idx];
        vuu[i] = H[2][idx];
        vvv[i] = H[3][idx];
    }

    const float C1 = 1.0e-4f;   // (0.01*1)^2
    const float C2 = 9.0e-4f;   // (0.03*1)^2
    float lsum = 0.0f;
    #pragma unroll
    for (int k = 0; k < 4; ++k) {
        float au = 0.f, av = 0.f, auu = 0.f, avv = 0.f;
        #pragma unroll
        for (int j = 0; j < KS; ++j) {
            au  = fmaf(g[j], vu [k + j], au);
            av  = fmaf(g[j], vv [k + j], av);
            auu = fmaf(g[j], vuu[k + j], auu);
            avv = fmaf(g[j], vvv[k + j], avv);
        }
        const float u2 = au * au;        // muu^2
        const float v2 = av * av;        // muv^2
        const float A  = u2 - v2;        // 4*mux*muy
        const float B  = u2 + v2;        // 2*(mux^2+muy^2)
        const float Cd = auu - avv;      // 4*conv(xy)
        const float Cs = auu + avv;      // 2*(conv(x^2)+conv(y^2))
        const float num1 = fmaf(0.5f, A, C1);        // 2 mux muy + C1
        const float den1 = fmaf(0.5f, B, C1);        // mux^2+muy^2 + C1
        const float num2 = fmaf(0.5f, Cd - A, C2);   // 2 sigma_xy + C2
        const float den2 = fmaf(0.5f, Cs - B, C2);   // sx2+sy2 + C2
        lsum = fmaf(num1 * num2, __builtin_amdgcn_rcpf(den1 * den2), lsum);
    }

    // ---- block reduction ----
    #pragma unroll
    for (int off = 32; off > 0; off >>= 1)
        lsum += __shfl_down(lsum, off, 64);

    const int lane = tid & 63;
    const int wid  = tid >> 6;
    if (lane == 0) wsum[wid] = lsum;
    __syncthreads();
    if (tid == 0)
        partial[bid] = wsum[0] + wsum[1] + wsum[2] + wsum[3];
}

// ---------------- final reduction ----------------
__global__ __launch_bounds__(1024) void ssim_reduce_kernel(
    const float* __restrict__ partial, int n, float* __restrict__ out)
{
    const int tid = threadIdx.x;
    double s = 0.0;
    for (int i = tid; i < n; i += 1024) s += (double)partial[i];

    #pragma unroll
    for (int off = 32; off > 0; off >>= 1)
        s += __shfl_down(s, off, 64);

    __shared__ double dsum[16];
    const int lane = tid & 63;
    const int wid  = tid >> 6;
    if (lane == 0) dsum[wid] = s;
    __syncthreads();
    if (tid == 0) {
        double total = 0.0;
        #pragma unroll
        for (int w = 0; w < 16; ++w) total += dsum[w];
        out[0] = (float)(1.0 - total / TOTAL_N);
    }
}

extern "C" void kernel_launch(void* const* d_in, const int* in_sizes, int n_in,
                              void* d_out, int out_size, void* d_ws, size_t ws_size,
                              hipStream_t stream) {
    const float* pred = (const float*)d_in[0];
    const float* targ = (const float*)d_in[1];
    const float* k2d  = (const float*)d_in[2];
    float* out = (float*)d_out;
    float* ws  = (float*)d_ws;   // NBLOCKS partial sums

    ssim_tile_kernel<<<NBLOCKS, 256, 0, stream>>>(pred, targ, k2d, ws);
    ssim_reduce_kernel<<<1, 1024, 0, stream>>>(ws, NBLOCKS, out);
}

// Round 9
// 172.619 us; speedup vs baseline: 3.0977x; 3.0977x over previous
//
#include <hip/hip_runtime.h>
#include <math.h>

#define IMG_H 512
#define IMG_W 512
#define N_IMG 96            // 32 * 3
#define TW 32               // tile width (output cols)
#define TH 32               // tile height (output rows)
#define KS 11
#define IN_ROWS 42          // TH + 10
#define NUNITS (IN_ROWS * 8)    // 336 horizontal-conv units (4 px each)
#define STRIDE 33           // odd LDS row stride -> 2-way banks (free)
#define PLANE (IN_ROWS * STRIDE)   // 1386
#define NBLOCKS (N_IMG * (IMG_W / TW) * (IMG_H / TH))   // 96*256 = 24576
#define TOTAL_N 25165824.0  // 32*3*512*512

// Round-9: round-7 design, but __launch_bounds__(256,4).
// Round-8 lesson: (256,6) capped VGPR at ~85, allocator landed at 40 and
// spilled 2.4 GB to scratch (FETCH 1.1 GB, WRITE 1.2 GB, VALUBusy 19%).
// (256,4) allows 128 VGPR -> no spill (round 5: VGPR=52 at same cap).
//  - u/v basis: u=x+y, v=x-y. FOUR conv maps: conv(u),conv(v),conv(u^2),conv(v^2)
//      2*mux*muy = (muu^2-muv^2)/2, mux^2+muy^2 = (muu^2+muv^2)/2,
//      conv(xy) = (Suu-Svv)/4, conv(x^2)+conv(y^2) = (Suu+Svv)/2.
//  - 32x32 tiles: h-pass halo overhead 1.31x (was 1.625 at 64x16).
//  - Gather-then-convolve (round 6 proved streaming schedules worse).
//  - LDS: 4 planes * 1386 * 4B = 22.2 KB.
//  - Bank conflicts measured 0 at this layout (round 8).

__global__ __launch_bounds__(256, 4) void ssim_tile_kernel(
    const float* __restrict__ pred, const float* __restrict__ targ,
    const float* __restrict__ k2d, float* __restrict__ partial)
{
    __shared__ float H[4][PLANE];
    __shared__ float wsum[4];

    const int tid = threadIdx.x;
    const int bid = blockIdx.x;
    const int img = bid >> 8;          // 256 tiles per image
    const int tin = bid & 255;
    const int ty  = tin >> 4;          // 16 tiles per dim
    const int tx  = tin & 15;
    const int y0  = ty * TH;
    const int x0  = tx * TW;

    // exact 1D gaussian from the 2D kernel: k2d[5][j] = g5 * g[j], k2d[5][5] = g5^2
    float g[KS];
    {
        const float inv = rsqrtf(k2d[5 * KS + 5]);
        #pragma unroll
        for (int j = 0; j < KS; ++j) g[j] = k2d[5 * KS + j] * inv;
    }

    const float* __restrict__ Pimg = pred + (size_t)img * (IMG_H * IMG_W);
    const float* __restrict__ Timg = targ + (size_t)img * (IMG_H * IMG_W);

    // ---- stage 1: horizontal 11-tap pass on u,v,u^2,v^2 -> LDS planes ----
    #pragma unroll
    for (int b = 0; b < 2; ++b) {
        const int u = tid + (b << 8);
        if (u < NUNITS) {
            const int r    = u >> 3;           // 0..41
            const int cg   = u & 7;            // 0..7
            const int gr   = y0 - 5 + r;
            const int col0 = x0 + (cg << 2) - 8;   // 16B-aligned window start
            const bool rowok = ((unsigned)gr < (unsigned)IMG_H);
            const float* rowP = Pimg + (size_t)(rowok ? gr : 0) * IMG_W;
            const float* rowT = Timg + (size_t)(rowok ? gr : 0) * IMG_W;

            float p[20], t[20];
            if (rowok && col0 >= 0 && col0 + 20 <= IMG_W) {
                #pragma unroll
                for (int q = 0; q < 5; ++q) {
                    const float4 vp = *(const float4*)(rowP + col0 + 4 * q);
                    const float4 vt = *(const float4*)(rowT + col0 + 4 * q);
                    p[4*q+0] = vp.x; p[4*q+1] = vp.y; p[4*q+2] = vp.z; p[4*q+3] = vp.w;
                    t[4*q+0] = vt.x; t[4*q+1] = vt.y; t[4*q+2] = vt.z; t[4*q+3] = vt.w;
                }
            } else {
                #pragma unroll
                for (int e = 0; e < 20; ++e) {
                    const int c  = col0 + e;
                    const int cc = min(max(c, 0), IMG_W - 1);
                    const bool ok = rowok && (c >= 0) && (c < IMG_W);
                    const float pv = rowP[cc];
                    const float tv = rowT[cc];
                    p[e] = ok ? pv : 0.0f;
                    t[e] = ok ? tv : 0.0f;
                }
            }

            // transform to u,v in place over the used range (elems 3..17)
            #pragma unroll
            for (int i = 0; i < 15; ++i) {
                const float pv = p[3 + i];
                const float tv = t[3 + i];
                p[3 + i] = pv + tv;     // u
                t[3 + i] = pv - tv;     // v
            }

            // mu convs of u,v
            float au[4], av[4];
            #pragma unroll
            for (int k = 0; k < 4; ++k) { au[k] = 0.f; av[k] = 0.f; }
            #pragma unroll
            for (int k = 0; k < 4; ++k) {
                #pragma unroll
                for (int j = 0; j < KS; ++j) {
                    au[k] = fmaf(g[j], p[3 + k + j], au[k]);
                    av[k] = fmaf(g[j], t[3 + k + j], av[k]);
                }
            }
            // square in place, then second-moment convs
            #pragma unroll
            for (int i = 0; i < 15; ++i) {
                p[3 + i] *= p[3 + i];   // u^2
                t[3 + i] *= t[3 + i];   // v^2
            }
            float auu[4], avv[4];
            #pragma unroll
            for (int k = 0; k < 4; ++k) { auu[k] = 0.f; avv[k] = 0.f; }
            #pragma unroll
            for (int k = 0; k < 4; ++k) {
                #pragma unroll
                for (int j = 0; j < KS; ++j) {
                    auu[k] = fmaf(g[j], p[3 + k + j], auu[k]);
                    avv[k] = fmaf(g[j], t[3 + k + j], avv[k]);
                }
            }

            const int wb = r * STRIDE + (cg << 2);
            #pragma unroll
            for (int e = 0; e < 4; ++e) {
                H[0][wb + e] = au[e];
                H[1][wb + e] = av[e];
                H[2][wb + e] = auu[e];
                H[3][wb + e] = avv[e];
            }
        }
    }
    __syncthreads();

    // ---- stage 2: vertical 11-tap pass + SSIM formula ----
    const int col  = tid & 31;
    const int rg   = tid >> 5;          // 0..7, rows rg*4 .. rg*4+3
    const int base = rg * 4 * STRIDE + col;

    float vu[14], vv[14], vuu[14], vvv[14];
    #pragma unroll
    for (int i = 0; i < 14; ++i) {
        const int idx = base + i * STRIDE;
        vu [i] = H[0][idx];
        vv [i] = H[1][idx];
        vuu[i] = H[2][idx];
        vvv[i] = H[3][idx];
    }

    const float C1 = 1.0e-4f;   // (0.01*1)^2
    const float C2 = 9.0e-4f;   // (0.03*1)^2
    float lsum = 0.0f;
    #pragma unroll
    for (int k = 0; k < 4; ++k) {
        float au = 0.f, av = 0.f, auu = 0.f, avv = 0.f;
        #pragma unroll
        for (int j = 0; j < KS; ++j) {
            au  = fmaf(g[j], vu [k + j], au);
            av  = fmaf(g[j], vv [k + j], av);
            auu = fmaf(g[j], vuu[k + j], auu);
            avv = fmaf(g[j], vvv[k + j], avv);
        }
        const float u2 = au * au;        // muu^2
        const float v2 = av * av;        // muv^2
        const float A  = u2 - v2;        // 4*mux*muy
        const float B  = u2 + v2;        // 2*(mux^2+muy^2)
        const float Cd = auu - avv;      // 4*conv(xy)
        const float Cs = auu + avv;      // 2*(conv(x^2)+conv(y^2))
        const float num1 = fmaf(0.5f, A, C1);        // 2 mux muy + C1
        const float den1 = fmaf(0.5f, B, C1);        // mux^2+muy^2 + C1
        const float num2 = fmaf(0.5f, Cd - A, C2);   // 2 sigma_xy + C2
        const float den2 = fmaf(0.5f, Cs - B, C2);   // sx2+sy2 + C2
        lsum = fmaf(num1 * num2, __builtin_amdgcn_rcpf(den1 * den2), lsum);
    }

    // ---- block reduction ----
    #pragma unroll
    for (int off = 32; off > 0; off >>= 1)
        lsum += __shfl_down(lsum, off, 64);

    const int lane = tid & 63;
    const int wid  = tid >> 6;
    if (lane == 0) wsum[wid] = lsum;
    __syncthreads();
    if (tid == 0)
        partial[bid] = wsum[0] + wsum[1] + wsum[2] + wsum[3];
}

// ---------------- final reduction ----------------
__global__ __launch_bounds__(1024) void ssim_reduce_kernel(
    const float* __restrict__ partial, int n, float* __restrict__ out)
{
    const int tid = threadIdx.x;
    double s = 0.0;
    for (int i = tid; i < n; i += 1024) s += (double)partial[i];

    #pragma unroll
    for (int off = 32; off > 0; off >>= 1)
        s += __shfl_down(s, off, 64);

    __shared__ double dsum[16];
    const int lane = tid & 63;
    const int wid  = tid >> 6;
    if (lane == 0) dsum[wid] = s;
    __syncthreads();
    if (tid == 0) {
        double total = 0.0;
        #pragma unroll
        for (int w = 0; w < 16; ++w) total += dsum[w];
        out[0] = (float)(1.0 - total / TOTAL_N);
    }
}

extern "C" void kernel_launch(void* const* d_in, const int* in_sizes, int n_in,
                              void* d_out, int out_size, void* d_ws, size_t ws_size,
                              hipStream_t stream) {
    const float* pred = (const float*)d_in[0];
    const float* targ = (const float*)d_in[1];
    const float* k2d  = (const float*)d_in[2];
    float* out = (float*)d_out;
    float* ws  = (float*)d_ws;   // NBLOCKS partial sums

    ssim_tile_kernel<<<NBLOCKS, 256, 0, stream>>>(pred, targ, k2d, ws);
    ssim_reduce_kernel<<<1, 1024, 0, stream>>>(ws, NBLOCKS, out);
}